// Round 2
// baseline (355.359 us; speedup 1.0000x reference)
//
#include <hip/hip_runtime.h>
#include <math.h>

// Problem constants (from reference setup): T=4, B=64, N=1024, P=63, D=128
#define T_STEPS 4
#define R_ROWS  65536              // B*N rows per timestep
#define M_ROWS  262144             // T*B*N total rows
#define P_DIM   63
#define D_DIM   128
#define PP      64                 // padded P (col 63 = virtual ones column in K1)

#define GRAM_BLOCKS 1024
#define G_COPIES 8
#define TILES_TOTAL (M_ROWS / 64)                    // 4096 tiles of 64 rows
#define TILES_PER_BLOCK (TILES_TOTAL / GRAM_BLOCKS)  // 4

// ---------------------------------------------------------------------------
// K1: G = xa^T xa  (xa = x with appended ones column, 64x64 fp64 result)
// Row/col 63 of G holds per-column sums of x (for the mean); G[63][63] = M.
// fp32 accumulation per 64-row tile -> per-thread fp64 -> fp64 atomics into
// one of 8 G copies (shortens per-address atomic chains to 128 RMWs).
// ---------------------------------------------------------------------------
__global__ __launch_bounds__(256) void gram_kernel(const float* __restrict__ x,
                                                   double* __restrict__ G) {
    __shared__ __align__(16) float xt[64 * PP];
    const int tid = threadIdx.x;
    const int tj = tid & 15;       // 16 col-tiles of 4
    const int ti = tid >> 4;       // 16 row-tiles of 4

    double dacc[4][4];
#pragma unroll
    for (int a = 0; a < 4; a++)
#pragma unroll
        for (int b = 0; b < 4; b++) dacc[a][b] = 0.0;

    if (tid < 64) xt[tid * PP + 63] = 1.0f;   // ones column (never overwritten)

    const int tile0 = blockIdx.x * TILES_PER_BLOCK;
    for (int tile = tile0; tile < tile0 + TILES_PER_BLOCK; tile++) {
        __syncthreads();
        // stage 64 rows x 63 cols = 1008 float4, coalesced flat load
        const float4* src = (const float4*)(x + (size_t)tile * (64 * 63));
#pragma unroll
        for (int it = 0; it < 4; it++) {
            int k = tid + it * 256;
            if (k < 1008) {
                float4 v = src[k];
                const float* ve = (const float*)&v;
                int flat = k * 4;
#pragma unroll
                for (int e = 0; e < 4; e++) {
                    int f = flat + e;
                    int r = f / 63;
                    int c = f - r * 63;
                    xt[r * PP + c] = ve[e];
                }
            }
        }
        __syncthreads();

        float facc[4][4];
#pragma unroll
        for (int a = 0; a < 4; a++)
#pragma unroll
            for (int b = 0; b < 4; b++) facc[a][b] = 0.0f;

        for (int r = 0; r < 64; r++) {
            float4 xi = *(const float4*)&xt[r * PP + ti * 4];
            float4 xj = *(const float4*)&xt[r * PP + tj * 4];
            const float* xia = (const float*)&xi;
            const float* xja = (const float*)&xj;
#pragma unroll
            for (int a = 0; a < 4; a++)
#pragma unroll
                for (int b = 0; b < 4; b++)
                    facc[a][b] = fmaf(xia[a], xja[b], facc[a][b]);
        }
#pragma unroll
        for (int a = 0; a < 4; a++)
#pragma unroll
            for (int b = 0; b < 4; b++) dacc[a][b] += (double)facc[a][b];
    }

    double* Gc = G + (size_t)(blockIdx.x & (G_COPIES - 1)) * (64 * 64);
#pragma unroll
    for (int a = 0; a < 4; a++)
#pragma unroll
        for (int b = 0; b < 4; b++)
            atomicAdd(&Gc[(ti * 4 + a) * 64 + (tj * 4 + b)], dacc[a][b]);
}

// ---------------------------------------------------------------------------
// K2: per-channel stats.  mean_d = (colsum . W_d)/M ; E[h^2]_d = W_d G W_d^T / M
// var = E[h^2] - mean^2 (fp64; mean ~ 0.002 so no cancellation).
// stats[d] = {mean, invstd, gamma, beta} as float4.
// ---------------------------------------------------------------------------
__global__ __launch_bounds__(64) void stats_kernel(const double* __restrict__ G,
                                                   const float* __restrict__ W,
                                                   const float* __restrict__ gamma,
                                                   const float* __restrict__ beta,
                                                   float* __restrict__ stats) {
    const int d = blockIdx.x;    // 0..127
    const int p = threadIdx.x;   // 0..63
    __shared__ float sW[64];
    sW[p] = (p < P_DIM) ? W[d * P_DIM + p] : 0.0f;
    __syncthreads();

    double inner = 0.0;
#pragma unroll
    for (int c = 0; c < G_COPIES; c++) {
        const double* Gr = G + (size_t)c * (64 * 64) + p * 64;
        for (int q = 0; q < 64; q++) inner += Gr[q] * (double)sW[q];
    }

    double contrib = (double)sW[p] * inner;   // row 63 has w=0 -> no effect
    double ex2M = contrib;
#pragma unroll
    for (int off = 32; off > 0; off >>= 1) ex2M += __shfl_down(ex2M, off, 64);
    double meanM = __shfl(inner, 63, 64);     // ones-row dot W_d = colsum . W_d

    if (p == 0) {
        double mean = meanM / (double)M_ROWS;
        double ex2  = ex2M  / (double)M_ROWS;
        double var  = ex2 - mean * mean;
        float varf  = (float)var;
        float vpe   = varf + 1e-5f;                 // ref: fp32 var + fp32 eps
        float invstd = (float)(1.0 / sqrt((double)vpe));  // ~correctly-rounded rsqrt
        stats[d * 4 + 0] = (float)mean;
        stats[d * 4 + 1] = invstd;
        stats[d * 4 + 2] = gamma[d];
        stats[d * 4 + 3] = beta[d];
    }
}

// ---------------------------------------------------------------------------
// K3: on-the-fly GEMM (sequential ascending-p fmaf, BLAS-like order) + BN
// affine in reference op order + 4-step LIF in registers. Block = 16 spatial
// rows x all 4 timesteps x all 128 channels; thread = 2 rows x 4 ch x 4 t.
// sx kept in NATURAL stride-63 layout: staging is a flat conflict-free b128
// copy, and inner-loop reads hit 8 distinct banks (stride-64 was 8-way
// same-bank conflicted). sw padded to stride 132 (float4-aligned, no
// conflicts on write d-major or read p-major).
// ---------------------------------------------------------------------------
#define LIF_ROWS 16
#define SW_STRIDE 132
__global__ __launch_bounds__(256) void lif_kernel(const float* __restrict__ x,
                                                  const float* __restrict__ W,
                                                  const float* __restrict__ stats,
                                                  float* __restrict__ out) {
    __shared__ __align__(16) float sw[P_DIM * SW_STRIDE];        // [p][d] pad 132
    __shared__ __align__(16) float sx[T_STEPS * LIF_ROWS * P_DIM]; // natural layout
    const int tid = threadIdx.x;

    // stage W transposed (dest-major: conflict-free LDS writes; W is L1/L2-hot)
    for (int k = tid; k < P_DIM * D_DIM; k += 256) {
        int p = k >> 7;
        int d = k & 127;
        sw[p * SW_STRIDE + d] = W[d * P_DIM + p];
    }

    // stage x: 4 segments (one per t) of 16 rows x 63 = 252 float4 each,
    // flat copy (global layout == LDS layout), conflict-free b128 writes
    const int r0 = blockIdx.x * LIF_ROWS;
    const int seg = tid >> 6;
    const int lane = tid & 63;
    const float4* src = (const float4*)(x + ((size_t)seg * R_ROWS + r0) * P_DIM);
    float4* dst = (float4*)sx + seg * 252;
    for (int k = lane; k < 252; k += 64) {
        dst[k] = src[k];
    }
    __syncthreads();

    const int td = tid & 31;      // 32 channel-tiles of 4
    const int tr = tid >> 5;      // 8 row-pairs
    const int d0 = td * 4;
    const int rowa = tr * 2;

    float acc[T_STEPS][2][4];
#pragma unroll
    for (int t = 0; t < T_STEPS; t++)
#pragma unroll
        for (int i = 0; i < 2; i++)
#pragma unroll
            for (int j = 0; j < 4; j++) acc[t][i][j] = 0.0f;

    for (int p = 0; p < P_DIM; p++) {
        float4 w4 = *(const float4*)&sw[p * SW_STRIDE + d0];
#pragma unroll
        for (int t = 0; t < T_STEPS; t++)
#pragma unroll
            for (int i = 0; i < 2; i++) {
                float xv = sx[(t * LIF_ROWS + rowa + i) * P_DIM + p];
                acc[t][i][0] = fmaf(xv, w4.x, acc[t][i][0]);
                acc[t][i][1] = fmaf(xv, w4.y, acc[t][i][1]);
                acc[t][i][2] = fmaf(xv, w4.z, acc[t][i][2]);
                acc[t][i][3] = fmaf(xv, w4.w, acc[t][i][3]);
            }
    }

    // epilogue: BN affine (ref op order) + LIF scan; vectorized stores
#pragma unroll
    for (int i = 0; i < 2; i++) {
        const int row = r0 + rowa + i;
        float sval[T_STEPS][4];
#pragma unroll
        for (int j = 0; j < 4; j++) {
            float4 st = ((const float4*)stats)[d0 + j];  // mean, invstd, gamma, beta
            float v = 0.0f;
#pragma unroll
            for (int t = 0; t < T_STEPS; t++) {
                float hn = (acc[t][i][j] - st.x) * st.y;
                hn = hn * st.z;
                hn = hn + st.w;
                v = v + (hn - v) * 0.5f;       // == v + (x-v)/2, exact
                float s = (v >= 1.0f) ? 1.0f : 0.0f;  // (v-1>=0) sign-exact
                sval[t][j] = s;
                if (s != 0.0f) v = 0.0f;       // hard reset
            }
        }
#pragma unroll
        for (int t = 0; t < T_STEPS; t++) {
            float4 o = make_float4(sval[t][0], sval[t][1], sval[t][2], sval[t][3]);
            *(float4*)&out[((size_t)t * R_ROWS + row) * D_DIM + d0] = o;
        }
    }
}

// ---------------------------------------------------------------------------
extern "C" void kernel_launch(void* const* d_in, const int* in_sizes, int n_in,
                              void* d_out, int out_size, void* d_ws, size_t ws_size,
                              hipStream_t stream) {
    const float* x     = (const float*)d_in[0];
    const float* W     = (const float*)d_in[1];
    const float* gamma = (const float*)d_in[2];
    const float* beta  = (const float*)d_in[3];
    float* out = (float*)d_out;

    double* G    = (double*)d_ws;                        // 8 copies * 32768 B
    float* stats = (float*)((char*)d_ws + G_COPIES * 64 * 64 * 8);

    hipMemsetAsync(d_ws, 0, G_COPIES * 64 * 64 * 8, stream);
    gram_kernel<<<GRAM_BLOCKS, 256, 0, stream>>>(x, G);
    stats_kernel<<<D_DIM, 64, 0, stream>>>(G, W, gamma, beta, stats);
    lif_kernel<<<R_ROWS / LIF_ROWS, 256, 0, stream>>>(x, W, stats, out);
}

// Round 3
// 290.711 us; speedup vs baseline: 1.2224x; 1.2224x over previous
//
#include <hip/hip_runtime.h>
#include <math.h>

// Problem constants (from reference setup): T=4, B=64, N=1024, P=63, D=128
#define T_STEPS 4
#define R_ROWS  65536              // B*N rows per timestep
#define M_ROWS  262144             // T*B*N total rows
#define P_DIM   63
#define D_DIM   128
#define PP      64                 // padded P (col 63 = virtual ones column in K1)

#define TILES_TOTAL (M_ROWS / 64)  // 4096 tiles of 64 rows
#define G_CHUNKS 8                 // reduce output copies consumed by stats

// ---------------------------------------------------------------------------
// K1: per-block partial Gram  P_b = xa_b^T xa_b  (xa = x + ones column).
// Double-buffered LDS staging (register prefetch), fp32 per 64-row tile ->
// fp64 per-block, PLAIN coalesced stores of the 64x64 fp64 partial.
// NO global atomics: round-2 profiling showed fp64 atomics cost ~32 B HBM
// write each (XCD L2 line ping-pong) and serialized the whole kernel.
// ---------------------------------------------------------------------------
__global__ __launch_bounds__(256) void gram_kernel(const float* __restrict__ x,
                                                   double* __restrict__ partials,
                                                   int tiles_per_block) {
    __shared__ __align__(16) float xt[2][64 * PP];
    const int tid = threadIdx.x;
    const int tj = tid & 15;       // 16 col-tiles of 4
    const int ti = tid >> 4;       // 16 row-tiles of 4

    double dacc[4][4];
#pragma unroll
    for (int a = 0; a < 4; a++)
#pragma unroll
        for (int b = 0; b < 4; b++) dacc[a][b] = 0.0;

    if (tid < 64) {                // ones column in both buffers (never overwritten)
        xt[0][tid * PP + 63] = 1.0f;
        xt[1][tid * PP + 63] = 1.0f;
    }

    const int tile0 = blockIdx.x * tiles_per_block;
    float4 reg[4];

    // prefetch tile 0 -> regs
    {
        const float4* src = (const float4*)(x + (size_t)tile0 * (64 * 63));
#pragma unroll
        for (int it = 0; it < 4; it++) {
            int k = tid + it * 256;
            reg[it] = (k < 1008) ? src[k] : make_float4(0.f, 0.f, 0.f, 0.f);
        }
    }
    // regs -> LDS buf 0
#pragma unroll
    for (int it = 0; it < 4; it++) {
        int k = tid + it * 256;
        if (k < 1008) {
            const float* ve = (const float*)&reg[it];
            int flat = k * 4;
#pragma unroll
            for (int e = 0; e < 4; e++) {
                int f = flat + e;
                int r = f / 63;
                int c = f - r * 63;
                xt[0][r * PP + c] = ve[e];
            }
        }
    }
    __syncthreads();

    for (int t = 0; t < tiles_per_block; t++) {
        const int cur = t & 1;
        // issue prefetch of tile t+1 (lands during compute; waitcnt at LDS write)
        if (t + 1 < tiles_per_block) {
            const float4* src = (const float4*)(x + (size_t)(tile0 + t + 1) * (64 * 63));
#pragma unroll
            for (int it = 0; it < 4; it++) {
                int k = tid + it * 256;
                reg[it] = (k < 1008) ? src[k] : make_float4(0.f, 0.f, 0.f, 0.f);
            }
        }

        // compute on buffer cur
        float facc[4][4];
#pragma unroll
        for (int a = 0; a < 4; a++)
#pragma unroll
            for (int b = 0; b < 4; b++) facc[a][b] = 0.0f;

        const float* buf = xt[cur];
        for (int r = 0; r < 64; r++) {
            float4 xi = *(const float4*)&buf[r * PP + ti * 4];
            float4 xj = *(const float4*)&buf[r * PP + tj * 4];
            const float* xia = (const float*)&xi;
            const float* xja = (const float*)&xj;
#pragma unroll
            for (int a = 0; a < 4; a++)
#pragma unroll
                for (int b = 0; b < 4; b++)
                    facc[a][b] = fmaf(xia[a], xja[b], facc[a][b]);
        }
#pragma unroll
        for (int a = 0; a < 4; a++)
#pragma unroll
            for (int b = 0; b < 4; b++) dacc[a][b] += (double)facc[a][b];

        __syncthreads();           // all readers of buf[cur] (and prior buf[1-cur]) done
        if (t + 1 < tiles_per_block) {
            float* nbuf = xt[1 - cur];
#pragma unroll
            for (int it = 0; it < 4; it++) {
                int k = tid + it * 256;
                if (k < 1008) {
                    const float* ve = (const float*)&reg[it];
                    int flat = k * 4;
#pragma unroll
                    for (int e = 0; e < 4; e++) {
                        int f = flat + e;
                        int r = f / 63;
                        int c = f - r * 63;
                        nbuf[r * PP + c] = ve[e];
                    }
                }
            }
            __syncthreads();
        }
    }

    // plain coalesced stores of the fp64 partial
    double* Pb = partials + (size_t)blockIdx.x * 4096;
#pragma unroll
    for (int a = 0; a < 4; a++)
#pragma unroll
        for (int b = 0; b < 4; b++)
            Pb[(ti * 4 + a) * 64 + (tj * 4 + b)] = dacc[a][b];
}

// ---------------------------------------------------------------------------
// K1b: fold nparts partials into G_CHUNKS copies (deterministic fp64 sums,
// coalesced reads). grid = G_CHUNKS * 16 blocks of 256.
// ---------------------------------------------------------------------------
__global__ __launch_bounds__(256) void reduce_kernel(const double* __restrict__ partials,
                                                     double* __restrict__ G8,
                                                     int copies_per_chunk) {
    const int chunk = blockIdx.x >> 4;             // 0..7
    const int idx   = (blockIdx.x & 15) * 256 + threadIdx.x;  // 0..4095
    const double* src = partials + (size_t)chunk * copies_per_chunk * 4096;
    double s = 0.0;
    for (int c = 0; c < copies_per_chunk; c++)
        s += src[(size_t)c * 4096 + idx];
    G8[(size_t)chunk * 4096 + idx] = s;
}

// ---------------------------------------------------------------------------
// K2: per-channel stats.  mean_d = (colsum . W_d)/M ; E[h^2]_d = W_d G W_d^T / M
// var = E[h^2] - mean^2 (fp64; mean ~ 0.002 so no cancellation).
// stats[d] = {mean, invstd, gamma, beta} as float4.
// ---------------------------------------------------------------------------
__global__ __launch_bounds__(64) void stats_kernel(const double* __restrict__ G,
                                                   const float* __restrict__ W,
                                                   const float* __restrict__ gamma,
                                                   const float* __restrict__ beta,
                                                   float* __restrict__ stats) {
    const int d = blockIdx.x;    // 0..127
    const int p = threadIdx.x;   // 0..63
    __shared__ float sW[64];
    sW[p] = (p < P_DIM) ? W[d * P_DIM + p] : 0.0f;
    __syncthreads();

    double inner = 0.0;
#pragma unroll
    for (int c = 0; c < G_CHUNKS; c++) {
        const double* Gr = G + (size_t)c * (64 * 64) + p * 64;
        for (int q = 0; q < 64; q++) inner += Gr[q] * (double)sW[q];
    }

    double contrib = (double)sW[p] * inner;   // row 63 has w=0 -> no effect
    double ex2M = contrib;
#pragma unroll
    for (int off = 32; off > 0; off >>= 1) ex2M += __shfl_down(ex2M, off, 64);
    double meanM = __shfl(inner, 63, 64);     // ones-row dot W_d = colsum . W_d

    if (p == 0) {
        double mean = meanM / (double)M_ROWS;
        double ex2  = ex2M  / (double)M_ROWS;
        double var  = ex2 - mean * mean;
        float varf  = (float)var;
        float vpe   = varf + 1e-5f;                 // ref: fp32 var + fp32 eps
        float invstd = (float)(1.0 / sqrt((double)vpe));  // ~correctly-rounded rsqrt
        stats[d * 4 + 0] = (float)mean;
        stats[d * 4 + 1] = invstd;
        stats[d * 4 + 2] = gamma[d];
        stats[d * 4 + 3] = beta[d];
    }
}

// ---------------------------------------------------------------------------
// K3: on-the-fly GEMM (sequential ascending-p fmaf, BLAS-like order) + BN
// affine in reference op order + 4-step LIF in registers. Block = 16 spatial
// rows x all 4 timesteps x all 128 channels; thread = 2 rows x 4 ch x 4 t.
// sx in natural stride-63 layout (conflict-free both ways). sw staged with
// COALESCED global reads (sequential k), transpose on the LDS-write side.
// ---------------------------------------------------------------------------
#define LIF_ROWS 16
#define SW_STRIDE 132
__global__ __launch_bounds__(256) void lif_kernel(const float* __restrict__ x,
                                                  const float* __restrict__ W,
                                                  const float* __restrict__ stats,
                                                  float* __restrict__ out) {
    __shared__ __align__(16) float sw[P_DIM * SW_STRIDE];          // [p][d] pad 132
    __shared__ __align__(16) float sx[T_STEPS * LIF_ROWS * P_DIM + 4]; // natural layout
    const int tid = threadIdx.x;

    // stage W: sequential-k coalesced global reads; scatter-transpose into LDS
    for (int k = tid; k < P_DIM * D_DIM; k += 256) {
        int d = k / 63;            // magic-mul div
        int p = k - d * 63;
        sw[p * SW_STRIDE + d] = W[k];
    }

    // stage x: 4 segments (one per t) of 16 rows x 63 = 252 float4 each,
    // flat copy (global layout == LDS layout), conflict-free b128 writes
    const int r0 = blockIdx.x * LIF_ROWS;
    const int seg = tid >> 6;
    const int lane = tid & 63;
    const float4* src = (const float4*)(x + ((size_t)seg * R_ROWS + r0) * P_DIM);
    float4* dst = (float4*)sx + seg * 252;
    for (int k = lane; k < 252; k += 64) {
        dst[k] = src[k];
    }
    __syncthreads();

    const int td = tid & 31;      // 32 channel-tiles of 4
    const int tr = tid >> 5;      // 8 row-pairs
    const int d0 = td * 4;
    const int rowa = tr * 2;

    float acc[T_STEPS][2][4];
#pragma unroll
    for (int t = 0; t < T_STEPS; t++)
#pragma unroll
        for (int i = 0; i < 2; i++)
#pragma unroll
            for (int j = 0; j < 4; j++) acc[t][i][j] = 0.0f;

    for (int p = 0; p < P_DIM; p++) {
        float4 w4 = *(const float4*)&sw[p * SW_STRIDE + d0];
#pragma unroll
        for (int t = 0; t < T_STEPS; t++)
#pragma unroll
            for (int i = 0; i < 2; i++) {
                float xv = sx[(t * LIF_ROWS + rowa + i) * P_DIM + p];
                acc[t][i][0] = fmaf(xv, w4.x, acc[t][i][0]);
                acc[t][i][1] = fmaf(xv, w4.y, acc[t][i][1]);
                acc[t][i][2] = fmaf(xv, w4.z, acc[t][i][2]);
                acc[t][i][3] = fmaf(xv, w4.w, acc[t][i][3]);
            }
    }

    // epilogue: BN affine (ref op order) + LIF scan; vectorized stores
#pragma unroll
    for (int i = 0; i < 2; i++) {
        const int row = r0 + rowa + i;
        float sval[T_STEPS][4];
#pragma unroll
        for (int j = 0; j < 4; j++) {
            float4 st = ((const float4*)stats)[d0 + j];  // mean, invstd, gamma, beta
            float v = 0.0f;
#pragma unroll
            for (int t = 0; t < T_STEPS; t++) {
                float hn = (acc[t][i][j] - st.x) * st.y;
                hn = hn * st.z;
                hn = hn + st.w;
                v = v + (hn - v) * 0.5f;       // == v + (x-v)/2, exact
                float s = (v >= 1.0f) ? 1.0f : 0.0f;  // (v-1>=0) sign-exact
                sval[t][j] = s;
                if (s != 0.0f) v = 0.0f;       // hard reset
            }
        }
#pragma unroll
        for (int t = 0; t < T_STEPS; t++) {
            float4 o = make_float4(sval[t][0], sval[t][1], sval[t][2], sval[t][3]);
            *(float4*)&out[((size_t)t * R_ROWS + row) * D_DIM + d0] = o;
        }
    }
}

// ---------------------------------------------------------------------------
extern "C" void kernel_launch(void* const* d_in, const int* in_sizes, int n_in,
                              void* d_out, int out_size, void* d_ws, size_t ws_size,
                              hipStream_t stream) {
    const float* x     = (const float*)d_in[0];
    const float* W     = (const float*)d_in[1];
    const float* gamma = (const float*)d_in[2];
    const float* beta  = (const float*)d_in[3];
    float* out = (float*)d_out;

    // pick partial count by available workspace (power of 2, 64..512)
    const size_t fixed = (size_t)G_CHUNKS * 4096 * 8 + 4096;  // G8 + stats + pad
    int nparts = 512;
    while (nparts > 64 && (size_t)nparts * 4096 * 8 + fixed > ws_size) nparts >>= 1;
    const int tiles_per_block = TILES_TOTAL / nparts;

    double* partials = (double*)d_ws;
    double* G8       = (double*)((char*)d_ws + (size_t)nparts * 4096 * 8);
    float*  stats    = (float*)((char*)G8 + (size_t)G_CHUNKS * 4096 * 8);

    gram_kernel<<<nparts, 256, 0, stream>>>(x, partials, tiles_per_block);
    reduce_kernel<<<G_CHUNKS * 16, 256, 0, stream>>>(partials, G8, nparts / G_CHUNKS);
    stats_kernel<<<D_DIM, 64, 0, stream>>>(G8, W, gamma, beta, stats);
    lif_kernel<<<R_ROWS / LIF_ROWS, 256, 0, stream>>>(x, W, stats, out);
}